// Round 1
// baseline (406.812 us; speedup 1.0000x reference)
//
#include <hip/hip_runtime.h>

#define BS   64
#define NQ   3000
#define NC   256
#define FH   100
#define FW   100
#define TOPK 1500

// ---------------- Kernel A: scores[b,q] = max_c class[b,q,c] ----------------
// One wave (64 lanes) per row; lane i loads float4 at element 4i (coalesced).
__global__ __launch_bounds__(256) void scores_kernel(const float4* __restrict__ cls,
                                                     float* __restrict__ scores) {
    int wave = threadIdx.x >> 6;
    int lane = threadIdx.x & 63;
    int row  = blockIdx.x * 4 + wave;
    if (row >= BS * NQ) return;
    float4 v = cls[(size_t)row * (NC / 4) + lane];
    float m = fmaxf(fmaxf(v.x, v.y), fmaxf(v.z, v.w));
#pragma unroll
    for (int off = 32; off > 0; off >>= 1)
        m = fmaxf(m, __shfl_down(m, off, 64));
    if (lane == 0) scores[row] = m;
}

// ---------------- Kernel B: per-batch top-k select + rect raster + mask -----
__global__ __launch_bounds__(256) void mask_kernel(const float4* __restrict__ coord,
                                                   const int* __restrict__ vfs,
                                                   const float* __restrict__ scores,
                                                   float* __restrict__ out) {
    __shared__ unsigned su[NQ];       // score bit patterns (positive -> uint order == float order)
    __shared__ unsigned cov[FH * 4];  // 100 rows x 128-bit column bitmask
    __shared__ int      eqc[256];
    __shared__ int      cnt;

    const int b   = blockIdx.x;
    const int tid = threadIdx.x;

    for (int q = tid; q < NQ; q += 256)
        su[q] = __float_as_uint(scores[b * NQ + q]);
    for (int i = tid; i < FH * 4; i += 256)
        cov[i] = 0u;
    __syncthreads();

    // Radix select: v = max{x : count(su >= x) >= TOPK}  (== TOPK-th largest value)
    unsigned prefix = 0u;
    for (int bit = 30; bit >= 0; --bit) {
        unsigned cand = prefix | (1u << bit);
        if (tid == 0) cnt = 0;
        __syncthreads();
        int c = 0;
        for (int q = tid; q < NQ; q += 256) c += (su[q] >= cand) ? 1 : 0;
        atomicAdd(&cnt, c);
        __syncthreads();
        if (cnt >= TOPK) prefix = cand;
        __syncthreads();
    }
    const unsigned v = prefix;

    // G = count strictly greater; take first (TOPK-G) equals by index (stable tie-break)
    if (tid == 0) cnt = 0;
    __syncthreads();
    {
        int c = 0;
        for (int q = tid; q < NQ; q += 256) c += (su[q] > v) ? 1 : 0;
        atomicAdd(&cnt, c);
    }
    __syncthreads();
    const int e_take = TOPK - cnt;

    // Contiguous-chunk partition so equal-ranks are in index order.
    const int CHUNK = (NQ + 255) / 256;  // 12
    const int q0 = tid * CHUNK;
    const int q1 = (q0 + CHUNK < NQ) ? q0 + CHUNK : NQ;
    int ec = 0;
    for (int q = q0; q < q1; ++q) ec += (su[q] == v) ? 1 : 0;
    eqc[tid] = ec;
    __syncthreads();
    if (tid == 0) {
        int r = 0;
        for (int i = 0; i < 256; ++i) { int t = eqc[i]; eqc[i] = r; r += t; }
    }
    __syncthreads();
    int rank = eqc[tid];

    const float s0 = (float)vfs[2 * b];      // reference scales x by vfs[:,0] (height!)
    const float s1 = (float)vfs[2 * b + 1];  // and y by vfs[:,1] (width!) — replicate

    for (int q = q0; q < q1; ++q) {
        unsigned sv = su[q];
        bool sel = false;
        if (sv > v) sel = true;
        else if (sv == v) { sel = (rank < e_take); ++rank; }
        if (!sel) continue;

        float4 c4 = coord[(size_t)b * NQ + q];  // (cx, cy, w, h)
        float x1 = c4.x - 0.5f * c4.z;
        float y1 = c4.y - 0.5f * c4.w;
        float x2 = c4.x + 0.5f * c4.z;
        float y2 = c4.y + 0.5f * c4.w;
        int lx = (int)floorf(x1 * s0);
        int ly = (int)floorf(y1 * s1);
        int rx = (int)floorf(x2 * s0);
        int ry = (int)floorf(y2 * s1);
        int h0 = ly > 0 ? ly : 0;
        int h1 = ry < FH ? ry : FH;
        int w0 = lx > 0 ? lx : 0;
        int w1 = rx < FW ? rx : FW;
        if (h0 >= h1 || w0 >= w1) continue;

        unsigned m[4];
#pragma unroll
        for (int j = 0; j < 4; ++j) {
            int lo = w0 - 32 * j; lo = lo < 0 ? 0 : lo;
            int hi = w1 - 32 * j; hi = hi > 32 ? 32 : hi;
            unsigned mm = 0u;
            if (hi > lo) {
                unsigned top = (hi >= 32) ? 0xFFFFFFFFu : ((1u << hi) - 1u);
                unsigned bot = (lo <= 0) ? 0u : ((1u << lo) - 1u);
                mm = top & ~bot;
            }
            m[j] = mm;
        }
        for (int h = h0; h < h1; ++h) {
#pragma unroll
            for (int j = 0; j < 4; ++j)
                if (m[j]) atomicOr(&cov[h * 4 + j], m[j]);
        }
    }
    __syncthreads();

    // Output: 0 where covered && !pad, else -1e20. Padding recomputed from vfs.
    const int iv0 = vfs[2 * b], iv1 = vfs[2 * b + 1];
    for (int idx = tid; idx < FH * FW; idx += 256) {
        int h = idx / FW;
        int w = idx - h * FW;
        bool covered = (cov[h * 4 + (w >> 5)] >> (w & 31)) & 1u;
        bool pad = (h >= iv0) || (w >= iv1);
        out[(size_t)b * (FH * FW) + idx] = (covered && !pad) ? 0.0f : -1e20f;
    }
}

extern "C" void kernel_launch(void* const* d_in, const int* in_sizes, int n_in,
                              void* d_out, int out_size, void* d_ws, size_t ws_size,
                              hipStream_t stream) {
    const float4* coord  = (const float4*)d_in[0];   // (BS, NQ, 4) f32
    const float*  cls    = (const float*)d_in[1];    // (BS, NQ, NC) f32
    const int*    vfs    = (const int*)d_in[2];      // (BS, 2) i32
    // d_in[3] (padding_mask) ignored — recomputed from vfs.
    float* scores = (float*)d_ws;                    // BS*NQ floats
    float* out    = (float*)d_out;

    const int rows = BS * NQ;
    scores_kernel<<<(rows + 3) / 4, 256, 0, stream>>>((const float4*)cls, scores);
    mask_kernel<<<BS, 256, 0, stream>>>(coord, vfs, scores, out);
}